// Round 1
// baseline (282.010 us; speedup 1.0000x reference)
//
#include <hip/hip_runtime.h>

// Q4_0 quantized linear: out[T, OUT] = x[T, IN] @ ((w_q - 8) * w_scale).T + bias
// T=16, IN=4096, OUT=11008. All fp32 (w_q int32 values in [0,16)).
//
// Strategy: split-K GEMV. Each block: 256 threads <-> 256 output rows,
// k-chunk of 256. w tile transposed through padded LDS (coalesced global
// reads, conflict-free column reads). x chunk staged as xs[k][token] so the
// 16 token values are fetched with same-address float4 broadcasts (free).
// Partial sums combined across k-splits with fp32 atomicAdd; out zeroed by
// a graph-captured hipMemsetAsync; bias added by the k-split-0 blocks.

constexpr int TOKENS = 16;
constexpr int ROWS   = 256;  // output rows per block == threads per block
constexpr int CK     = 256;  // k-elements per block (split-K chunk)
constexpr int WSUB   = 32;   // k sub-chunk of the w tile staged per iteration
constexpr int WPAD   = 33;   // ws row stride (odd -> bank-conflict-free column reads)
constexpr int XPAD   = 20;   // xs row stride in floats (80 B -> float4-aligned)

__global__ __launch_bounds__(ROWS) void qlinear_splitk(
    const float* __restrict__ x,        // [T, IN]
    const int*   __restrict__ w_q,      // [OUT, IN]
    const float* __restrict__ w_scale,  // [OUT, IN/32]
    const float* __restrict__ bias,     // [OUT]
    float* __restrict__ out,            // [T, OUT] (pre-zeroed)
    int in_f, int out_f)
{
    __shared__ float xs[CK][XPAD];   // 256*20*4 = 20 KiB
    __shared__ int   ws[ROWS][WPAD]; // 256*33*4 = 33.8 KiB

    const int tid  = threadIdx.x;
    const int row0 = blockIdx.x * ROWS;
    const int k0   = blockIdx.y * CK;
    const int row  = row0 + tid;

    // Stage x chunk transposed: xs[i][t] = x[t][k0+i]. Coalesced global reads.
    #pragma unroll
    for (int t = 0; t < TOKENS; ++t)
        xs[tid][t] = x[(size_t)t * in_f + k0 + tid];

    float acc[TOKENS];
    #pragma unroll
    for (int t = 0; t < TOKENS; ++t) acc[t] = 0.0f;

    const int nscale = in_f >> 5;  // scales per row

    for (int sub = 0; sub < CK / WSUB; ++sub) {
        __syncthreads();  // protect ws reuse (also covers xs on first trip)

        // Stage w tile [ROWS][WSUB] ints. 2048 int4 loads: 8 per thread.
        // flat int4 id f: row = f/8, int4-within-row j = f%8 -> lanes 0..7
        // read 128 contiguous bytes of one row (well coalesced).
        #pragma unroll
        for (int it = 0; it < (ROWS * WSUB / 4) / ROWS; ++it) {
            int f = it * ROWS + tid;
            int r = f >> 3;
            int j = f & 7;
            const int4* src =
                (const int4*)(w_q + (size_t)(row0 + r) * in_f + k0 + sub * WSUB);
            int4 v = src[j];
            ws[r][j * 4 + 0] = v.x;
            ws[r][j * 4 + 1] = v.y;
            ws[r][j * 4 + 2] = v.z;
            ws[r][j * 4 + 3] = v.w;
        }
        __syncthreads();

        // One scale per row per 32-k sub-chunk (WSUB == Q4_0 block size).
        float s  = w_scale[(size_t)row * nscale + (k0 >> 5) + sub];
        float s8 = -8.0f * s;  // exact (power of two times s)

        #pragma unroll
        for (int i = 0; i < WSUB; ++i) {
            // (q - 8) * s with a single rounding
            float wv = fmaf((float)ws[tid][i], s, s8);
            const float4* xp = (const float4*)(&xs[sub * WSUB + i][0]);
            float4 x0 = xp[0], x1 = xp[1], x2 = xp[2], x3 = xp[3];
            acc[0]  = fmaf(wv, x0.x, acc[0]);
            acc[1]  = fmaf(wv, x0.y, acc[1]);
            acc[2]  = fmaf(wv, x0.z, acc[2]);
            acc[3]  = fmaf(wv, x0.w, acc[3]);
            acc[4]  = fmaf(wv, x1.x, acc[4]);
            acc[5]  = fmaf(wv, x1.y, acc[5]);
            acc[6]  = fmaf(wv, x1.z, acc[6]);
            acc[7]  = fmaf(wv, x1.w, acc[7]);
            acc[8]  = fmaf(wv, x2.x, acc[8]);
            acc[9]  = fmaf(wv, x2.y, acc[9]);
            acc[10] = fmaf(wv, x2.z, acc[10]);
            acc[11] = fmaf(wv, x2.w, acc[11]);
            acc[12] = fmaf(wv, x3.x, acc[12]);
            acc[13] = fmaf(wv, x3.y, acc[13]);
            acc[14] = fmaf(wv, x3.z, acc[14]);
            acc[15] = fmaf(wv, x3.w, acc[15]);
        }
    }

    if (blockIdx.y == 0) {  // add bias exactly once per output
        float b = bias[row];
        #pragma unroll
        for (int t = 0; t < TOKENS; ++t) acc[t] += b;
    }

    #pragma unroll
    for (int t = 0; t < TOKENS; ++t)
        atomicAdd(out + (size_t)t * out_f + row, acc[t]);
}

extern "C" void kernel_launch(void* const* d_in, const int* in_sizes, int n_in,
                              void* d_out, int out_size, void* d_ws, size_t ws_size,
                              hipStream_t stream) {
    const float* x       = (const float*)d_in[0];
    const int*   w_q     = (const int*)d_in[1];
    const float* w_scale = (const float*)d_in[2];
    const float* bias    = (const float*)d_in[3];
    float*       out     = (float*)d_out;

    const int out_f = in_sizes[3];            // 11008
    const int in_f  = in_sizes[1] / out_f;    // 4096

    // Zero the (0xAA-poisoned) output; captured as a graph memset node.
    hipMemsetAsync(d_out, 0, (size_t)out_size * sizeof(float), stream);

    dim3 grid(out_f / ROWS, in_f / CK);       // 43 x 16 = 688 blocks
    qlinear_splitk<<<grid, ROWS, 0, stream>>>(x, w_q, w_scale, bias, out,
                                              in_f, out_f);
}

// Round 2
// 278.474 us; speedup vs baseline: 1.0127x; 1.0127x over previous
//
#include <hip/hip_runtime.h>

// Q4_0 quantized linear: out[16, 11008] = x[16, 4096] @ ((w_q-8)*w_scale).T + bias
// All fp32; w_q holds int32 nibble values in [0,16).
//
// R=4 row-blocked split-K GEMV. Block: 256 threads own 1024 output rows
// (thread t owns rows t, t+256, t+512, t+768), k-chunk CK=128 split in 4
// stages of 32 (= Q4_0 block). w is packed to BYTES in LDS (4 values per
// ds_read_b32, row stride 36 B -> 2-way bank aliasing = free). x chunk is
// staged transposed so the 16 token values per k come from 4 same-address
// (broadcast) float4 reads, amortized over 4 output rows (64 FMAs).
// Partials combined across 32 k-splits with fp32 atomicAdd; out zeroed by a
// graph-captured memset; bias added by the split-0 blocks.

constexpr int T       = 16;
constexpr int IN      = 4096;
constexpr int OUT     = 11008;
constexpr int NSCALE  = IN / 32;        // 128 scales per row
constexpr int THREADS = 256;
constexpr int R       = 4;              // rows per thread
constexpr int ROWSB   = THREADS * R;    // 1024 rows per block
constexpr int CK      = 128;            // k per block (split-K chunk)
constexpr int WSUB    = 32;             // k per stage (== Q4_0 block size)
constexpr int WSTRIDE = 36;             // ws8 row stride bytes (32 + 4 pad -> 9 words)
constexpr int XPAD    = 20;             // xs row stride floats (80 B, 16B-aligned)

__global__ __launch_bounds__(THREADS) void qlinear_r4(
    const float* __restrict__ x,        // [T, IN]
    const int*   __restrict__ w_q,      // [OUT, IN]
    const float* __restrict__ w_scale,  // [OUT, NSCALE]
    const float* __restrict__ bias,     // [OUT]
    float* __restrict__ out)            // [T, OUT] (pre-zeroed)
{
    __shared__ __align__(16) float         xs[CK][XPAD];       // 10.0 KiB
    __shared__ __align__(16) unsigned char ws8[ROWSB * WSTRIDE]; // 36 KiB

    const int tid  = threadIdx.x;
    const int row0 = blockIdx.x * ROWSB;
    const int k0   = blockIdx.y * CK;

    // ---- stage x chunk transposed: xs[k][t] = x[t][k0+k] (coalesced) ----
    #pragma unroll
    for (int it = 0; it < CK * T / THREADS; ++it) {  // 8
        int idx = it * THREADS + tid;
        int t   = idx >> 7;          // idx / CK
        int k   = idx & (CK - 1);
        xs[k][t] = x[t * IN + k0 + k];
    }

    // ---- per-row scales for the 4 sub-blocks of this k-chunk ----
    float4 sc[R];
    #pragma unroll
    for (int r = 0; r < R; ++r) {
        int rg = min(row0 + tid + r * THREADS, OUT - 1);
        sc[r] = *(const float4*)(w_scale + rg * NSCALE + (k0 >> 5));
    }

    float acc[R][T];
    #pragma unroll
    for (int r = 0; r < R; ++r)
        #pragma unroll
        for (int t = 0; t < T; ++t) acc[r][t] = 0.0f;

    #pragma unroll
    for (int sub = 0; sub < CK / WSUB; ++sub) {      // 4
        __syncthreads();   // protect ws8 reuse (covers xs on first trip)

        // ---- stage w tile: 1024 rows x 32 ints -> packed bytes in LDS ----
        // flat int4 id f: row rr = f/8, j = f%8; lanes 0..7 read 128
        // contiguous bytes of one row (fully coalesced dwordx4 loads).
        #pragma unroll 4
        for (int it = 0; it < (ROWSB * WSUB / 4) / THREADS; ++it) {  // 32
            int f  = it * THREADS + tid;
            int rr = f >> 3;
            int j  = f & 7;
            int rg = min(row0 + rr, OUT - 1);
            const int4 v = *(const int4*)(w_q + rg * IN + k0 + sub * WSUB + j * 4);
            unsigned int u = (unsigned)v.x | ((unsigned)v.y << 8) |
                             ((unsigned)v.z << 16) | ((unsigned)v.w << 24);
            *(unsigned int*)(ws8 + rr * WSTRIDE + j * 4) = u;
        }
        __syncthreads();

        float s[R], s8[R];
        #pragma unroll
        for (int r = 0; r < R; ++r) {
            float sv = (sub == 0) ? sc[r].x : (sub == 1) ? sc[r].y
                     : (sub == 2) ? sc[r].z : sc[r].w;   // sub is constant
            s[r]  = sv;
            s8[r] = -8.0f * sv;   // exact
        }

        for (int k4 = 0; k4 < WSUB / 4; ++k4) {      // 8 (rolled)
            unsigned int q[R];
            #pragma unroll
            for (int r = 0; r < R; ++r)
                q[r] = *(const unsigned int*)(ws8 + (tid + r * THREADS) * WSTRIDE + k4 * 4);

            #pragma unroll
            for (int kk = 0; kk < 4; ++kk) {
                const float4* xp = (const float4*)&xs[sub * WSUB + k4 * 4 + kk][0];
                float4 x0 = xp[0], x1 = xp[1], x2 = xp[2], x3 = xp[3];
                #pragma unroll
                for (int r = 0; r < R; ++r) {
                    // (q - 8) * s with a single rounding; byte extract is
                    // kk-constant -> v_cvt_f32_ubyte{kk}
                    float wv = fmaf((float)((q[r] >> (8 * kk)) & 0xffu), s[r], s8[r]);
                    acc[r][0]  = fmaf(wv, x0.x, acc[r][0]);
                    acc[r][1]  = fmaf(wv, x0.y, acc[r][1]);
                    acc[r][2]  = fmaf(wv, x0.z, acc[r][2]);
                    acc[r][3]  = fmaf(wv, x0.w, acc[r][3]);
                    acc[r][4]  = fmaf(wv, x1.x, acc[r][4]);
                    acc[r][5]  = fmaf(wv, x1.y, acc[r][5]);
                    acc[r][6]  = fmaf(wv, x1.z, acc[r][6]);
                    acc[r][7]  = fmaf(wv, x1.w, acc[r][7]);
                    acc[r][8]  = fmaf(wv, x2.x, acc[r][8]);
                    acc[r][9]  = fmaf(wv, x2.y, acc[r][9]);
                    acc[r][10] = fmaf(wv, x2.z, acc[r][10]);
                    acc[r][11] = fmaf(wv, x2.w, acc[r][11]);
                    acc[r][12] = fmaf(wv, x3.x, acc[r][12]);
                    acc[r][13] = fmaf(wv, x3.y, acc[r][13]);
                    acc[r][14] = fmaf(wv, x3.z, acc[r][14]);
                    acc[r][15] = fmaf(wv, x3.w, acc[r][15]);
                }
            }
        }
    }

    // ---- epilogue: bias (split 0 only) + atomic combine across splits ----
    const bool add_b = (blockIdx.y == 0);
    #pragma unroll
    for (int r = 0; r < R; ++r) {
        int rg = row0 + tid + r * THREADS;
        if (rg < OUT) {
            float b = add_b ? bias[rg] : 0.0f;
            #pragma unroll
            for (int t = 0; t < T; ++t)
                atomicAdd(out + t * OUT + rg, acc[r][t] + b);
        }
    }
}

extern "C" void kernel_launch(void* const* d_in, const int* in_sizes, int n_in,
                              void* d_out, int out_size, void* d_ws, size_t ws_size,
                              hipStream_t stream) {
    const float* x       = (const float*)d_in[0];
    const int*   w_q     = (const int*)d_in[1];
    const float* w_scale = (const float*)d_in[2];
    const float* bias    = (const float*)d_in[3];
    float*       out     = (float*)d_out;

    // Zero the (0xAA-poisoned) output; captured as a graph memset node.
    hipMemsetAsync(d_out, 0, (size_t)out_size * sizeof(float), stream);

    dim3 grid((OUT + ROWSB - 1) / ROWSB, IN / CK);   // 11 x 32 = 352 blocks
    qlinear_r4<<<grid, THREADS, 0, stream>>>(x, w_q, w_scale, bias, out);
}